// Round 1
// baseline (1674.509 us; speedup 1.0000x reference)
//
#include <hip/hip_runtime.h>

// Problem constants (fixed by the reference file)
#define BB   32      // batch
#define TT   512     // time
#define II   128     // input dim
#define HH   128     // hidden per rnn
#define NR   16      // num independent rnn blocks
#define HTOT 2048    // HH * NR

// One workgroup per (rnn-block n, batch b) cell. 128 threads; thread g owns
// output unit j = n*128+g. Both weight rows (W_ih row j, W_hh diagonal-block
// row) live in registers (~256 VGPR -> 1 wave/SIMD; grid 512 blocks = 4
// waves/CU exactly fills that occupancy). h_{t-1} is double-buffered in LDS,
// read via same-address broadcast (conflict-free). The x-projection for step
// t+1 is computed during step t so global-load latency hides under the
// recurrent FMA chain.
__global__ __launch_bounds__(128, 1) void msml_fused(
    const float* __restrict__ x,     // (B, T, I)
    const float* __restrict__ Wih,   // (HTOT, I)
    const float* __restrict__ Whh,   // (HTOT, HTOT)
    const float* __restrict__ bih,   // (HTOT)
    const float* __restrict__ bhh,   // (HTOT)
    float* __restrict__ out)         // hs_all (B,T,HTOT) then hidden (B,HTOT)
{
    const int n = blockIdx.x;        // 0..15  rnn block
    const int b = blockIdx.y;        // 0..31  batch
    const int g = threadIdx.x;       // 0..127 output unit within block
    const int j = n * HH + g;        // global hidden index

    // ---- load weight rows into registers (fully unrolled, static indices) ----
    float wih[II];
    float whh[HH];
    {
        const float4* wi4 = reinterpret_cast<const float4*>(Wih + (size_t)j * II);
        const float4* wh4 = reinterpret_cast<const float4*>(Whh + (size_t)j * HTOT + n * HH);
#pragma unroll
        for (int k = 0; k < II / 4; ++k) {
            float4 v = wi4[k];
            wih[4*k+0] = v.x; wih[4*k+1] = v.y; wih[4*k+2] = v.z; wih[4*k+3] = v.w;
        }
#pragma unroll
        for (int k = 0; k < HH / 4; ++k) {
            float4 v = wh4[k];
            whh[4*k+0] = v.x; whh[4*k+1] = v.y; whh[4*k+2] = v.z; whh[4*k+3] = v.w;
        }
    }
    const float bias = bih[j] + bhh[j];

    __shared__ float hs[2][HH];
    hs[0][g] = 0.0f;

    const float* xrow = x + (size_t)b * TT * II;             // step stride II
    float* orow = out + (size_t)b * TT * HTOT + (size_t)n * HH + g;

    // x-projection for t=0 (pipeline prologue)
    float accx;
    {
        const float4* xv = reinterpret_cast<const float4*>(xrow);
        float a = bias;
#pragma unroll
        for (int k = 0; k < II / 4; ++k) {
            float4 v = xv[k];
            a += wih[4*k+0]*v.x + wih[4*k+1]*v.y + wih[4*k+2]*v.z + wih[4*k+3]*v.w;
        }
        accx = a;
    }
    __syncthreads();   // hs[0] visible

    float hn = 0.0f;
    for (int t = 0; t < TT; ++t) {
        // ---- x-projection for step t+1 (loads issue early, consumed next iter) ----
        float accx_next = bias;
        if (t + 1 < TT) {
            const float4* xv = reinterpret_cast<const float4*>(xrow + (size_t)(t + 1) * II);
            float a = bias;
#pragma unroll
            for (int k = 0; k < II / 4; ++k) {
                float4 v = xv[k];
                a += wih[4*k+0]*v.x + wih[4*k+1]*v.y + wih[4*k+2]*v.z + wih[4*k+3]*v.w;
            }
            accx_next = a;
        }

        // ---- recurrent contribution: dot(whh_row, h_{t-1}) via LDS broadcast ----
        const float4* hv = reinterpret_cast<const float4*>(hs[t & 1]);
        float acc = accx;
#pragma unroll
        for (int k = 0; k < HH / 4; ++k) {
            float4 v = hv[k];
            acc += whh[4*k+0]*v.x + whh[4*k+1]*v.y + whh[4*k+2]*v.z + whh[4*k+3]*v.w;
        }

        hn = fmaxf(acc, 0.0f);
        orow[(size_t)t * HTOT] = hn;        // coalesced 512B per block
        hs[(t + 1) & 1][g] = hn;            // next step's h_{t-1}
        accx = accx_next;
        __syncthreads();                    // one barrier per step (double buffer)
    }

    // hidden = h at t = T-1, shape (1, B, HTOT) appended after hs_all
    out[(size_t)BB * TT * HTOT + (size_t)b * HTOT + j] = hn;
}

extern "C" void kernel_launch(void* const* d_in, const int* in_sizes, int n_in,
                              void* d_out, int out_size, void* d_ws, size_t ws_size,
                              hipStream_t stream) {
    const float* x   = (const float*)d_in[0];
    const float* Wih = (const float*)d_in[1];
    const float* Whh = (const float*)d_in[2];
    const float* bih = (const float*)d_in[3];
    const float* bhh = (const float*)d_in[4];
    float* out = (float*)d_out;

    dim3 grid(NR, BB);   // 16 x 32 = 512 workgroups
    dim3 block(128);
    msml_fused<<<grid, block, 0, stream>>>(x, Wih, Whh, bih, bhh, out);
}

// Round 2
// 665.948 us; speedup vs baseline: 2.5145x; 2.5145x over previous
//
#include <hip/hip_runtime.h>

// Problem constants (fixed by the reference file)
#define BB   32      // batch
#define TT   512     // time
#define II   128     // input dim
#define HH   128     // hidden per rnn
#define NR   16      // num independent rnn blocks
#define HTOT 2048    // HH * NR

// One workgroup per (rnn-block n, batch b) cell, 512 threads = 8 waves.
// Thread layout: output unit j = wave*16 + (lane&15)  (128 units),
//                K-slice    s = lane>>4               (4 slices).
// Slice s owns the interleaved float4 chunks c = 4k+s (k=0..7) of the K=128
// dot, so each thread keeps only 32+32 weight floats in registers (~120 VGPR,
// no spill, 4 waves/SIMD occupancy), the FMA dependency chain is 8 deep
// (4 accumulators), LDS reads of the 4 slice groups hit disjoint bank quads,
// and the 4 groups' x-loads merge into single 64B cachelines per wave.
// Slice partials reduce via shfl_xor(16/32); x[t+1] is prefetched into
// registers at the top of each step so global latency hides under the h-dot.
__global__ __launch_bounds__(512, 4) void msml_fused2(
    const float* __restrict__ x,     // (B, T, I)
    const float* __restrict__ Wih,   // (HTOT, I)
    const float* __restrict__ Whh,   // (HTOT, HTOT)
    const float* __restrict__ bih,   // (HTOT)
    const float* __restrict__ bhh,   // (HTOT)
    float* __restrict__ out)         // hs_all (B,T,HTOT) then hidden (B,HTOT)
{
    const int n    = blockIdx.x;         // 0..15  rnn block
    const int b    = blockIdx.y;         // 0..31  batch
    const int tid  = threadIdx.x;
    const int wave = tid >> 6;           // 0..7
    const int lane = tid & 63;
    const int s    = lane >> 4;          // K-slice 0..3
    const int j    = wave * 16 + (lane & 15);  // output unit 0..127
    const int row  = n * HH + j;         // global hidden index

    // ---- per-thread weight slices (interleaved chunks 4k+s) ----
    float wih[32], whh[32];
    {
        const float4* wi4 = reinterpret_cast<const float4*>(Wih + (size_t)row * II);
        const float4* wh4 = reinterpret_cast<const float4*>(Whh + (size_t)row * HTOT + n * HH);
#pragma unroll
        for (int k = 0; k < 8; ++k) {
            float4 a = wi4[4 * k + s];
            wih[4*k+0] = a.x; wih[4*k+1] = a.y; wih[4*k+2] = a.z; wih[4*k+3] = a.w;
            float4 c = wh4[4 * k + s];
            whh[4*k+0] = c.x; whh[4*k+1] = c.y; whh[4*k+2] = c.z; whh[4*k+3] = c.w;
        }
    }
    const float bias0 = (s == 0) ? (bih[row] + bhh[row]) : 0.0f;

    __shared__ float hs[2][HH];
    if (tid < HH) hs[0][tid] = 0.0f;

    const float* xrow = x + (size_t)b * TT * II;
    float* orow = out + (size_t)b * TT * HTOT + (size_t)n * HH + j;

    // ---- x-projection for t=0 (prologue) ----
    float accx;
    {
        const float4* xv = reinterpret_cast<const float4*>(xrow);
        float a0 = bias0, a1 = 0.f, a2 = 0.f, a3 = 0.f;
#pragma unroll
        for (int k = 0; k < 8; ++k) {
            float4 v = xv[4 * k + s];
            a0 += wih[4*k+0] * v.x; a1 += wih[4*k+1] * v.y;
            a2 += wih[4*k+2] * v.z; a3 += wih[4*k+3] * v.w;
        }
        accx = (a0 + a1) + (a2 + a3);
    }
    __syncthreads();   // hs[0] visible

    float hn = 0.0f;
    int buf = 0;
    for (int t = 0; t < TT; ++t) {
        // ---- prefetch x chunks for t+1 (loads issue at top of the step) ----
        float4 xn[8];
        if (t + 1 < TT) {
            const float4* xv = reinterpret_cast<const float4*>(xrow + (size_t)(t + 1) * II);
#pragma unroll
            for (int k = 0; k < 8; ++k) xn[k] = xv[4 * k + s];
        }

        // ---- recurrent dot over this thread's K-slice (LDS broadcast) ----
        const float4* hv = reinterpret_cast<const float4*>(hs[buf]);
        float a0 = accx, a1 = 0.f, a2 = 0.f, a3 = 0.f;
#pragma unroll
        for (int k = 0; k < 8; ++k) {
            float4 v = hv[4 * k + s];
            a0 += whh[4*k+0] * v.x; a1 += whh[4*k+1] * v.y;
            a2 += whh[4*k+2] * v.z; a3 += whh[4*k+3] * v.w;
        }
        float sum = (a0 + a1) + (a2 + a3);
        sum += __shfl_xor(sum, 16);
        sum += __shfl_xor(sum, 32);
        hn = fmaxf(sum, 0.0f);

        if (s == 0) {
            orow[(size_t)t * HTOT] = hn;   // 512B contiguous per WG per step
            hs[buf ^ 1][j] = hn;           // next step's h_{t-1}
        }

        // ---- x-projection for t+1 from prefetched registers ----
        {
            float b0 = bias0, b1 = 0.f, b2 = 0.f, b3 = 0.f;
#pragma unroll
            for (int k = 0; k < 8; ++k) {
                b0 += wih[4*k+0] * xn[k].x; b1 += wih[4*k+1] * xn[k].y;
                b2 += wih[4*k+2] * xn[k].z; b3 += wih[4*k+3] * xn[k].w;
            }
            accx = (b0 + b1) + (b2 + b3);
        }

        buf ^= 1;
        __syncthreads();   // one barrier per step (double-buffered h)
    }

    // hidden = h at t = T-1, shape (1, B, HTOT) appended after hs_all
    if (s == 0)
        out[(size_t)BB * TT * HTOT + (size_t)b * HTOT + row] = hn;
}

extern "C" void kernel_launch(void* const* d_in, const int* in_sizes, int n_in,
                              void* d_out, int out_size, void* d_ws, size_t ws_size,
                              hipStream_t stream) {
    const float* x   = (const float*)d_in[0];
    const float* Wih = (const float*)d_in[1];
    const float* Whh = (const float*)d_in[2];
    const float* bih = (const float*)d_in[3];
    const float* bhh = (const float*)d_in[4];
    float* out = (float*)d_out;

    dim3 grid(NR, BB);   // 16 x 32 = 512 workgroups (one per rnn-block x batch)
    dim3 block(512);     // 8 waves
    msml_fused2<<<grid, block, 0, stream>>>(x, Wih, Whh, bih, bhh, out);
}

// Round 3
// 211.408 us; speedup vs baseline: 7.9208x; 3.1501x over previous
//
#include <hip/hip_runtime.h>
#include <hip/hip_bf16.h>

// Problem constants (fixed by the reference file)
#define BB   32      // batch
#define TT   512     // time
#define II   128     // input dim
#define HH   128     // hidden per rnn
#define NR   16      // num independent rnn blocks
#define HTOT 2048    // HH * NR

typedef __attribute__((ext_vector_type(8))) short short8;   // 8 bf16 (4 VGPR) MFMA A/B frag
typedef __attribute__((ext_vector_type(4))) float f32x4;    // MFMA C/D frag

static __device__ __forceinline__ short f2bf(float f) {
    union { __hip_bfloat16 h; short s; } u;
    u.h = __float2bfloat16(f);
    return u.s;
}
static __device__ __forceinline__ float bf2f(unsigned short u) {
    return __uint_as_float(((unsigned int)u) << 16);
}

// ---------------------------------------------------------------------------
// Kernel 1: pre = x @ W_ih^T + b_ih + b_hh, written bf16 to workspace in
// recurrence layout pre[(n*2+g)][t][m][j]  (g = batch group of 16, m = b&15).
// Full-chip MFMA GEMM: grid (128 M-tiles of 128 rows, 16 n). 8 waves/WG,
// wave w owns N-tile w (16 cols), iterates 8 M-tiles, K=128 as 4-chain.
// ---------------------------------------------------------------------------
__global__ __launch_bounds__(512, 2) void msml_pre(
    const float* __restrict__ x,     // (B,T,I)
    const float* __restrict__ Wih,   // (HTOT, II)
    const float* __restrict__ bih,
    const float* __restrict__ bhh,
    unsigned short* __restrict__ pre)
{
    const int mx = blockIdx.x;      // 0..127: 128-row tile of the 16384 (b,t) rows
    const int n  = blockIdx.y;      // 0..15
    const int tid = threadIdx.x;
    const int w = tid >> 6, l = tid & 63;
    const int q = l >> 4;           // k-group / row-group
    const int r0 = mx * 128;
    const int b  = r0 >> 9;         // one batch per 128-row tile (512/128=4 tiles)
    const int t0 = r0 & 511;
    const int g  = b >> 4, m = b & 15;

    __shared__ short A[128 * 136];  // x tile bf16, padded row stride 136

    // ---- stage x tile fp32 -> bf16 LDS ----
    {
        const int row = tid >> 2, cb = tid & 3;
        const float4* xs = reinterpret_cast<const float4*>(x + (size_t)(r0 + row) * II + cb * 32);
        short* dst = &A[row * 136 + cb * 32];
#pragma unroll
        for (int i = 0; i < 8; ++i) {
            float4 v = xs[i];
            *reinterpret_cast<short4*>(dst + 4 * i) =
                make_short4(f2bf(v.x), f2bf(v.y), f2bf(v.z), f2bf(v.w));
        }
    }

    // ---- B fragments: Wih rows for this wave's 16 cols, K=128, bf16 ----
    const int j = w * 16 + (l & 15);
    short8 bw[4];
    {
        const float* wb = Wih + (size_t)(n * HH + j) * II + q * 8;
#pragma unroll
        for (int kt = 0; kt < 4; ++kt) {
            float4 u0 = *reinterpret_cast<const float4*>(wb + kt * 32);
            float4 u1 = *reinterpret_cast<const float4*>(wb + kt * 32 + 4);
            short8 s;
            s[0] = f2bf(u0.x); s[1] = f2bf(u0.y); s[2] = f2bf(u0.z); s[3] = f2bf(u0.w);
            s[4] = f2bf(u1.x); s[5] = f2bf(u1.y); s[6] = f2bf(u1.z); s[7] = f2bf(u1.w);
            bw[kt] = s;
        }
    }
    const float bias = bih[n * HH + j] + bhh[n * HH + j];
    __syncthreads();

    const size_t ng = (size_t)(n * 2 + g);
#pragma unroll
    for (int mt = 0; mt < 8; ++mt) {
        const short* ap = &A[(mt * 16 + (l & 15)) * 136 + q * 8];
        f32x4 acc = {0.f, 0.f, 0.f, 0.f};
#pragma unroll
        for (int kt = 0; kt < 4; ++kt) {
            short8 a = *reinterpret_cast<const short8*>(ap + kt * 32);
            acc = __builtin_amdgcn_mfma_f32_16x16x32_bf16(a, bw[kt], acc, 0, 0, 0);
        }
#pragma unroll
        for (int r = 0; r < 4; ++r) {
            const int t = t0 + mt * 16 + q * 4 + r;   // C row = t offset within tile
            pre[((ng * TT + t) * 16 + m) * 128 + j] = (unsigned short)f2bf(acc[r] + bias);
        }
    }
}

// ---------------------------------------------------------------------------
// Kernel 2: recurrence. One WG per (n, batch-group g of 16): 32 WGs, 8 waves.
// H_t (16x128) = relu(Pre_t + H_{t-1} @ Wn^T) via 16x16x32 bf16 MFMA.
// Wave w owns output cols 16w..16w+15; Wn fragments live in registers for
// all 512 steps. H double-buffered in LDS [16][136] bf16 (pad -> <=2-way
// bank aliasing = free). One barrier per step. pre prefetched 2 steps ahead.
// ---------------------------------------------------------------------------
__global__ __launch_bounds__(512, 2) void msml_recur(
    const float* __restrict__ Whh,            // (HTOT, HTOT)
    const unsigned short* __restrict__ pre,   // bf16 (NR*2, TT, 16, 128)
    float* __restrict__ out)
{
    const int n = blockIdx.x;   // 0..15
    const int g = blockIdx.y;   // 0..1
    const int tid = threadIdx.x;
    const int w = tid >> 6, l = tid & 63;
    const int q = l >> 4;               // 0..3
    const int j = w * 16 + (l & 15);    // output col 0..127

    __shared__ short Hl[2][16 * 136];

    // ---- Wn^T B-fragments (diag block of Whh), fp32 -> bf16, regs forever ----
    short8 bw[4];
    {
        const float* wb = Whh + (size_t)(n * HH + j) * HTOT + n * HH + q * 8;
#pragma unroll
        for (int kt = 0; kt < 4; ++kt) {
            float4 u0 = *reinterpret_cast<const float4*>(wb + kt * 32);
            float4 u1 = *reinterpret_cast<const float4*>(wb + kt * 32 + 4);
            short8 s;
            s[0] = f2bf(u0.x); s[1] = f2bf(u0.y); s[2] = f2bf(u0.z); s[3] = f2bf(u0.w);
            s[4] = f2bf(u1.x); s[5] = f2bf(u1.y); s[6] = f2bf(u1.z); s[7] = f2bf(u1.w);
            bw[kt] = s;
        }
    }

    // zero H buffer 0 (h_{-1} = 0)
    for (int i = tid; i < 16 * 136; i += 512) Hl[0][i] = 0;

    // pre base for this thread: rows m = q*4 + r, col j
    const unsigned short* pb = pre + ((size_t)(n * 2 + g) * TT) * 2048 + (q * 4) * 128 + j;
    unsigned short pA0, pA1, pA2, pA3, pB0, pB1, pB2, pB3;
    { const unsigned short* pp = pb;        pA0 = pp[0]; pA1 = pp[128]; pA2 = pp[256]; pA3 = pp[384]; }
    { const unsigned short* pp = pb + 2048; pB0 = pp[0]; pB1 = pp[128]; pB2 = pp[256]; pB3 = pp[384]; }

    const size_t MS = (size_t)TT * HTOT;   // out stride per batch row
    float* ob = out + (size_t)(g * 16 + q * 4) * MS + n * HH + j;

    __syncthreads();   // Hl[0] zeros + (nothing else) visible

#define RSTEP(HRD, HWR, P0, P1, P2, P3, TCUR)                                      \
    {                                                                              \
        const short* hp = &HRD[(l & 15) * 136 + q * 8];                            \
        f32x4 acc = {0.f, 0.f, 0.f, 0.f};                                          \
        _Pragma("unroll")                                                          \
        for (int kt = 0; kt < 4; ++kt) {                                           \
            short8 a = *reinterpret_cast<const short8*>(hp + kt * 32);             \
            acc = __builtin_amdgcn_mfma_f32_16x16x32_bf16(a, bw[kt], acc, 0, 0, 0);\
        }                                                                          \
        float h0 = fmaxf(acc[0] + bf2f(P0), 0.f);                                  \
        float h1 = fmaxf(acc[1] + bf2f(P1), 0.f);                                  \
        float h2 = fmaxf(acc[2] + bf2f(P2), 0.f);                                  \
        float h3 = fmaxf(acc[3] + bf2f(P3), 0.f);                                  \
        { int tn = (TCUR) + 2 < TT ? (TCUR) + 2 : TT - 1;                          \
          const unsigned short* pp = pb + (size_t)tn * 2048;                       \
          P0 = pp[0]; P1 = pp[128]; P2 = pp[256]; P3 = pp[384]; }                  \
        float* oo = ob + (size_t)(TCUR) * HTOT;                                    \
        oo[0] = h0; oo[MS] = h1; oo[2 * MS] = h2; oo[3 * MS] = h3;                 \
        HWR[(q * 4 + 0) * 136 + j] = f2bf(h0);                                     \
        HWR[(q * 4 + 1) * 136 + j] = f2bf(h1);                                     \
        HWR[(q * 4 + 2) * 136 + j] = f2bf(h2);                                     \
        HWR[(q * 4 + 3) * 136 + j] = f2bf(h3);                                     \
        if ((TCUR) == TT - 1) {                                                    \
            float* hh = out + (size_t)BB * TT * HTOT                               \
                        + (size_t)(g * 16 + q * 4) * HTOT + n * HH + j;            \
            hh[0] = h0; hh[HTOT] = h1; hh[2 * HTOT] = h2; hh[3 * HTOT] = h3;       \
        }                                                                          \
        __syncthreads();                                                           \
    }

    short* hb0 = &Hl[0][0];
    short* hb1 = &Hl[1][0];
    for (int t = 0; t < TT; t += 2) {
        RSTEP(hb0, hb1, pA0, pA1, pA2, pA3, t)
        RSTEP(hb1, hb0, pB0, pB1, pB2, pB3, t + 1)
    }
#undef RSTEP
}

// ---------------------------------------------------------------------------
// Fallback (round-2 kernel, known-good): used if ws_size is too small.
// ---------------------------------------------------------------------------
__global__ __launch_bounds__(512, 4) void msml_fused2(
    const float* __restrict__ x,
    const float* __restrict__ Wih,
    const float* __restrict__ Whh,
    const float* __restrict__ bih,
    const float* __restrict__ bhh,
    float* __restrict__ out)
{
    const int n    = blockIdx.x;
    const int b    = blockIdx.y;
    const int tid  = threadIdx.x;
    const int wave = tid >> 6;
    const int lane = tid & 63;
    const int s    = lane >> 4;
    const int j    = wave * 16 + (lane & 15);
    const int row  = n * HH + j;

    float wih[32], whh[32];
    {
        const float4* wi4 = reinterpret_cast<const float4*>(Wih + (size_t)row * II);
        const float4* wh4 = reinterpret_cast<const float4*>(Whh + (size_t)row * HTOT + n * HH);
#pragma unroll
        for (int k = 0; k < 8; ++k) {
            float4 a = wi4[4 * k + s];
            wih[4*k+0] = a.x; wih[4*k+1] = a.y; wih[4*k+2] = a.z; wih[4*k+3] = a.w;
            float4 c = wh4[4 * k + s];
            whh[4*k+0] = c.x; whh[4*k+1] = c.y; whh[4*k+2] = c.z; whh[4*k+3] = c.w;
        }
    }
    const float bias0 = (s == 0) ? (bih[row] + bhh[row]) : 0.0f;

    __shared__ float hs[2][HH];
    if (tid < HH) hs[0][tid] = 0.0f;

    const float* xrow = x + (size_t)b * TT * II;
    float* orow = out + (size_t)b * TT * HTOT + (size_t)n * HH + j;

    float accx;
    {
        const float4* xv = reinterpret_cast<const float4*>(xrow);
        float a0 = bias0, a1 = 0.f, a2 = 0.f, a3 = 0.f;
#pragma unroll
        for (int k = 0; k < 8; ++k) {
            float4 v = xv[4 * k + s];
            a0 += wih[4*k+0] * v.x; a1 += wih[4*k+1] * v.y;
            a2 += wih[4*k+2] * v.z; a3 += wih[4*k+3] * v.w;
        }
        accx = (a0 + a1) + (a2 + a3);
    }
    __syncthreads();

    float hn = 0.0f;
    int buf = 0;
    for (int t = 0; t < TT; ++t) {
        float4 xn[8];
        if (t + 1 < TT) {
            const float4* xv = reinterpret_cast<const float4*>(xrow + (size_t)(t + 1) * II);
#pragma unroll
            for (int k = 0; k < 8; ++k) xn[k] = xv[4 * k + s];
        }
        const float4* hv = reinterpret_cast<const float4*>(hs[buf]);
        float a0 = accx, a1 = 0.f, a2 = 0.f, a3 = 0.f;
#pragma unroll
        for (int k = 0; k < 8; ++k) {
            float4 v = hv[4 * k + s];
            a0 += whh[4*k+0] * v.x; a1 += whh[4*k+1] * v.y;
            a2 += whh[4*k+2] * v.z; a3 += whh[4*k+3] * v.w;
        }
        float sum = (a0 + a1) + (a2 + a3);
        sum += __shfl_xor(sum, 16);
        sum += __shfl_xor(sum, 32);
        hn = fmaxf(sum, 0.0f);

        if (s == 0) {
            orow[(size_t)t * HTOT] = hn;
            hs[buf ^ 1][j] = hn;
        }
        {
            float b0 = bias0, b1 = 0.f, b2 = 0.f, b3 = 0.f;
#pragma unroll
            for (int k = 0; k < 8; ++k) {
                b0 += wih[4*k+0] * xn[k].x; b1 += wih[4*k+1] * xn[k].y;
                b2 += wih[4*k+2] * xn[k].z; b3 += wih[4*k+3] * xn[k].w;
            }
            accx = (b0 + b1) + (b2 + b3);
        }
        buf ^= 1;
        __syncthreads();
    }

    if (s == 0)
        out[(size_t)BB * TT * HTOT + (size_t)b * HTOT + row] = hn;
}

extern "C" void kernel_launch(void* const* d_in, const int* in_sizes, int n_in,
                              void* d_out, int out_size, void* d_ws, size_t ws_size,
                              hipStream_t stream) {
    const float* x   = (const float*)d_in[0];
    const float* Wih = (const float*)d_in[1];
    const float* Whh = (const float*)d_in[2];
    const float* bih = (const float*)d_in[3];
    const float* bhh = (const float*)d_in[4];
    float* out = (float*)d_out;

    const size_t pre_bytes = (size_t)NR * 2 * TT * 16 * 128 * sizeof(unsigned short); // 64 MiB

    if (ws_size >= pre_bytes && d_ws != nullptr) {
        unsigned short* pre = (unsigned short*)d_ws;
        msml_pre<<<dim3(128, NR), 512, 0, stream>>>(x, Wih, bih, bhh, pre);
        msml_recur<<<dim3(NR, 2), 512, 0, stream>>>(Whh, pre, out);
    } else {
        msml_fused2<<<dim3(NR, BB), 512, 0, stream>>>(x, Wih, Whh, bih, bhh, out);
    }
}